// Round 1
// baseline (818.761 us; speedup 1.0000x reference)
//
#include <hip/hip_runtime.h>
#include <hip/hip_bf16.h>
#include <math.h>

#define VOCAB 50000
#define DDIM 256
#define EDIM 256
#define HDIM 128
#define N_MEM 2000
#define MEM_WORDS 50
#define BATCH 64
#define Q_LEN 50
#define N_CHOICE 4
#define CH_LEN 10
#define NT 5            /* targets per batch row: q + 4 answer choices */
#define BT (BATCH * NT) /* 320 */

__device__ __forceinline__ float sigmoidf_(float x) {
    return 1.0f / (1.0f + expf(-x));
}

/* ---------------- generic 32x32-tiled transpose: out[C][R] = in[R][C] -------- */
__global__ __launch_bounds__(256) void transpose_kernel(const float* __restrict__ in,
                                                        float* __restrict__ out,
                                                        int R, int C) {
    __shared__ float tile[32][33];
    int c0 = blockIdx.x * 32, r0 = blockIdx.y * 32;
    int tx = threadIdx.x & 31, ty = threadIdx.x >> 5; // ty: 0..7
    for (int i = ty; i < 32; i += 8) {
        int r = r0 + i, c = c0 + tx;
        tile[i][tx] = (r < R && c < C) ? in[(size_t)r * C + c] : 0.0f;
    }
    __syncthreads();
    for (int i = ty; i < 32; i += 8) {
        int r = c0 + i, c = r0 + tx; // out is [C][R]
        if (r < C && c < R) out[(size_t)r * R + c] = tile[tx][i];
    }
}

/* ---------------- M[hop][n][d] = sum_w A_emb[hop][memory[n][w]][d] ----------- */
__global__ __launch_bounds__(256) void compute_M_kernel(const int* __restrict__ memory,
                                                        const float* __restrict__ A_emb,
                                                        float* __restrict__ M_all) {
    int n = blockIdx.x, hop = blockIdx.y, d = threadIdx.x;
    __shared__ int idx[MEM_WORDS];
    if (d < MEM_WORDS) idx[d] = memory[n * MEM_WORDS + d];
    __syncthreads();
    const float* base = A_emb + (size_t)hop * VOCAB * DDIM;
    float acc = 0.0f;
#pragma unroll 5
    for (int w = 0; w < MEM_WORDS; ++w) acc += base[(size_t)idx[w] * DDIM + d];
    M_all[((size_t)hop * N_MEM + n) * DDIM + d] = acc;
}

/* ---------------- a[b][k][d] = sum_w C_emb[ach[b][k][w]][d] ------------------ */
__global__ __launch_bounds__(256) void answer_bag_kernel(const int* __restrict__ ach,
                                                         const float* __restrict__ C_emb,
                                                         float* __restrict__ a) {
    int k = blockIdx.x, b = blockIdx.y, d = threadIdx.x;
    __shared__ int idx[CH_LEN];
    if (d < CH_LEN) idx[d] = ach[(b * N_CHOICE + k) * CH_LEN + d];
    __syncthreads();
    float acc = 0.0f;
#pragma unroll
    for (int w = 0; w < CH_LEN; ++w) acc += C_emb[(size_t)idx[w] * EDIM + d];
    a[(size_t)(b * N_CHOICE + k) * EDIM + d] = acc;
}

/* ---------------- C[M][N] = A[M][K] @ B[N][K]^T (+bias), optional A-row gather */
template <bool GATHER, bool BIAS>
__global__ __launch_bounds__(256) void gemm_abT_kernel(
    const float* __restrict__ A, const float* __restrict__ B, float* __restrict__ C,
    int M, int N, int K, const int* __restrict__ gidx,
    const float* __restrict__ bias1, const float* __restrict__ bias2) {
    __shared__ float As[16][64];
    __shared__ float Bs[16][64];
    __shared__ int rows[64];
    const int tid = threadIdx.x;
    const int m0 = blockIdx.x * 64;
    const int n0 = blockIdx.y * 64;
    const int lrow = tid >> 2;       // 0..63
    const int lk = (tid & 3) << 2;   // 0,4,8,12
    const int tx = tid & 15;
    const int ty = tid >> 4;
    if (GATHER) {
        if (tid < 64) rows[tid] = gidx[m0 + tid]; // M is a multiple of 64
        __syncthreads();
    }
    float acc[4][4] = {};
    for (int k0 = 0; k0 < K; k0 += 16) {
        const float* ap = GATHER ? (A + (size_t)rows[lrow] * K)
                                 : (A + (size_t)(m0 + lrow) * K);
        float4 av = *(const float4*)(ap + k0 + lk);
        float4 bv = make_float4(0.f, 0.f, 0.f, 0.f);
        int brow = n0 + lrow;
        if (brow < N) bv = *(const float4*)(B + (size_t)brow * K + k0 + lk);
        __syncthreads();
        As[lk + 0][lrow] = av.x; As[lk + 1][lrow] = av.y;
        As[lk + 2][lrow] = av.z; As[lk + 3][lrow] = av.w;
        Bs[lk + 0][lrow] = bv.x; Bs[lk + 1][lrow] = bv.y;
        Bs[lk + 2][lrow] = bv.z; Bs[lk + 3][lrow] = bv.w;
        __syncthreads();
#pragma unroll
        for (int kk = 0; kk < 16; ++kk) {
            float a0 = As[kk][ty * 4 + 0], a1 = As[kk][ty * 4 + 1];
            float a2 = As[kk][ty * 4 + 2], a3 = As[kk][ty * 4 + 3];
            float b0 = Bs[kk][tx * 4 + 0], b1 = Bs[kk][tx * 4 + 1];
            float b2 = Bs[kk][tx * 4 + 2], b3 = Bs[kk][tx * 4 + 3];
            acc[0][0] += a0 * b0; acc[0][1] += a0 * b1; acc[0][2] += a0 * b2; acc[0][3] += a0 * b3;
            acc[1][0] += a1 * b0; acc[1][1] += a1 * b1; acc[1][2] += a1 * b2; acc[1][3] += a1 * b3;
            acc[2][0] += a2 * b0; acc[2][1] += a2 * b1; acc[2][2] += a2 * b2; acc[2][3] += a2 * b3;
            acc[3][0] += a3 * b0; acc[3][1] += a3 * b1; acc[3][2] += a3 * b2; acc[3][3] += a3 * b3;
        }
    }
#pragma unroll
    for (int i = 0; i < 4; ++i) {
        int m = m0 + ty * 4 + i;
#pragma unroll
        for (int j = 0; j < 4; ++j) {
            int n = n0 + tx * 4 + j;
            if (n < N) {
                float v = acc[i][j];
                if (BIAS) v += bias1[n] + bias2[n];
                C[(size_t)m * N + n] = v;
            }
        }
    }
}

/* ---------------- Cpart[z][M][N] = A[M][kchunk] @ B[kchunk][N] (split-K) ------ */
__global__ __launch_bounds__(256) void gemm_ab_splitk_kernel(
    const float* __restrict__ A, const float* __restrict__ B, float* __restrict__ Cpart,
    int M, int N, int K, int KC) {
    __shared__ float As[16][64];
    __shared__ float Bs[16][64];
    const int tid = threadIdx.x;
    const int m0 = blockIdx.x * 64;
    const int n0 = blockIdx.y * 64;
    const int kstart = blockIdx.z * KC;
    const int kend = min(K, kstart + KC); // chunk spans are multiples of 16
    const int arow = tid >> 2;
    const int alk = (tid & 3) << 2;
    const int bk = tid >> 4;         // 0..15
    const int bn = (tid & 15) << 2;  // 0..60
    const int tx = tid & 15;
    const int ty = tid >> 4;
    float acc[4][4] = {};
    for (int k0 = kstart; k0 < kend; k0 += 16) {
        float4 av = *(const float4*)(A + (size_t)(m0 + arow) * K + k0 + alk);
        float4 bv = *(const float4*)(B + (size_t)(k0 + bk) * N + n0 + bn);
        __syncthreads();
        As[alk + 0][arow] = av.x; As[alk + 1][arow] = av.y;
        As[alk + 2][arow] = av.z; As[alk + 3][arow] = av.w;
        *(float4*)&Bs[bk][bn] = bv;
        __syncthreads();
#pragma unroll
        for (int kk = 0; kk < 16; ++kk) {
            float a0 = As[kk][ty * 4 + 0], a1 = As[kk][ty * 4 + 1];
            float a2 = As[kk][ty * 4 + 2], a3 = As[kk][ty * 4 + 3];
            float b0 = Bs[kk][tx * 4 + 0], b1 = Bs[kk][tx * 4 + 1];
            float b2 = Bs[kk][tx * 4 + 2], b3 = Bs[kk][tx * 4 + 3];
            acc[0][0] += a0 * b0; acc[0][1] += a0 * b1; acc[0][2] += a0 * b2; acc[0][3] += a0 * b3;
            acc[1][0] += a1 * b0; acc[1][1] += a1 * b1; acc[1][2] += a1 * b2; acc[1][3] += a1 * b3;
            acc[2][0] += a2 * b0; acc[2][1] += a2 * b1; acc[2][2] += a2 * b2; acc[2][3] += a2 * b3;
            acc[3][0] += a3 * b0; acc[3][1] += a3 * b1; acc[3][2] += a3 * b2; acc[3][3] += a3 * b3;
        }
    }
    float* Cz = Cpart + (size_t)blockIdx.z * M * N;
#pragma unroll
    for (int i = 0; i < 4; ++i)
#pragma unroll
        for (int j = 0; j < 4; ++j)
            Cz[(size_t)(m0 + ty * 4 + i) * N + n0 + tx * 4 + j] = acc[i][j];
}

/* ---------------- sequential LSTM; one block per batch, thread = gate -------- */
__global__ __launch_bounds__(512) void lstm_kernel(const float* __restrict__ G0,
                                                   const float* __restrict__ WhhT,
                                                   float* __restrict__ u) {
    const int b = blockIdx.x;
    const int j = threadIdx.x; // 0..511
    __shared__ float sh[HDIM];
    __shared__ float sc[HDIM];
    __shared__ float sg[4 * HDIM];
    if (j < HDIM) { sh[j] = 0.0f; sc[j] = 0.0f; }
    __syncthreads();
    for (int t = 0; t < Q_LEN; ++t) {
        float g = G0[((size_t)b * Q_LEN + t) * (4 * HDIM) + j];
#pragma unroll 4
        for (int h = 0; h < HDIM; ++h) g += WhhT[h * (4 * HDIM) + j] * sh[h];
        sg[j] = g;
        __syncthreads();
        if (j < HDIM) {
            float gi = sg[j], gf = sg[HDIM + j], gg = sg[2 * HDIM + j], go = sg[3 * HDIM + j];
            float c = sigmoidf_(gf) * sc[j] + sigmoidf_(gi) * tanhf(gg);
            sh[j] = sigmoidf_(go) * tanhf(c);
            sc[j] = c;
        }
        __syncthreads();
    }
    if (j < HDIM) {
        u[(size_t)b * EDIM + j] = sh[j];
        u[(size_t)b * EDIM + HDIM + j] = sc[j];
    }
}

/* ---------------- T[b*5+tgt][d]: U^T proj of u (tgt 0) / V^T proj of a ------- */
__global__ __launch_bounds__(256) void proj_T_kernel(const float* __restrict__ u,
                                                     const float* __restrict__ a,
                                                     const float* __restrict__ UT,
                                                     const float* __restrict__ VT,
                                                     float* __restrict__ T) {
    const int tgt = blockIdx.x; // 0..4
    const int b = blockIdx.y;
    const int d = threadIdx.x;
    __shared__ float sx[EDIM];
    const float* src = (tgt == 0) ? (u + (size_t)b * EDIM)
                                  : (a + (size_t)(b * N_CHOICE + tgt - 1) * EDIM);
    sx[d] = src[d];
    __syncthreads();
    const float* Wt = (tgt == 0) ? UT : VT;
    float acc = 0.0f;
#pragma unroll 4
    for (int e = 0; e < EDIM; ++e) acc += Wt[(size_t)e * DDIM + d] * sx[e];
    T[(size_t)(b * NT + tgt) * DDIM + d] = acc;
}

/* ---------------- row softmax over N elements, in place ---------------------- */
__global__ __launch_bounds__(256) void softmax_rows_kernel(float* __restrict__ S, int N) {
    const int row = blockIdx.x;
    float* x = S + (size_t)row * N;
    __shared__ float red[256];
    const int tid = threadIdx.x;
    float mx = -INFINITY;
    for (int i = tid; i < N; i += 256) mx = fmaxf(mx, x[i]);
    red[tid] = mx;
    __syncthreads();
    for (int s = 128; s > 0; s >>= 1) {
        if (tid < s) red[tid] = fmaxf(red[tid], red[tid + s]);
        __syncthreads();
    }
    mx = red[0];
    __syncthreads();
    float sum = 0.0f;
    for (int i = tid; i < N; i += 256) {
        float e = expf(x[i] - mx);
        x[i] = e;
        sum += e;
    }
    red[tid] = sum;
    __syncthreads();
    for (int s = 128; s > 0; s >>= 1) {
        if (tid < s) red[tid] += red[tid + s];
        __syncthreads();
    }
    float inv = 1.0f / red[0];
    for (int i = tid; i < N; i += 256) x[i] *= inv;
}

/* ---------------- reduce split-K partials; u += o_q; a += o_a ---------------- */
__global__ __launch_bounds__(256) void reduce_update_kernel(const float* __restrict__ Opart,
                                                            float* __restrict__ O,
                                                            float* __restrict__ u,
                                                            float* __restrict__ a) {
    const int bt = blockIdx.x;
    const int d = threadIdx.x;
    const size_t idx = (size_t)bt * DDIM + d;
    const size_t stride = (size_t)BT * DDIM;
    float v = Opart[idx] + Opart[stride + idx] + Opart[2 * stride + idx] + Opart[3 * stride + idx];
    O[idx] = v;
    const int b = bt / NT, t = bt % NT;
    if (t == 0) u[(size_t)b * EDIM + d] += v;
    else a[(size_t)(b * N_CHOICE + t - 1) * EDIM + d] += v;
}

/* ---------------- pred[b][k] = o_q^T W o_a[k]; log_softmax over k ------------ */
__global__ __launch_bounds__(256) void predict_kernel(const float* __restrict__ O,
                                                      const float* __restrict__ W,
                                                      float* __restrict__ out) {
    const int b = blockIdx.x;
    const int m = threadIdx.x;
    __shared__ float soq[DDIM];
    __shared__ float red[256];
    __shared__ float scv[N_CHOICE];
    soq[m] = O[(size_t)(b * NT) * DDIM + m];
    __syncthreads();
    float wq = 0.0f;
#pragma unroll 4
    for (int d = 0; d < DDIM; ++d) wq += W[(size_t)d * DDIM + m] * soq[d];
    for (int k = 0; k < N_CHOICE; ++k) {
        red[m] = wq * O[(size_t)(b * NT + 1 + k) * DDIM + m];
        __syncthreads();
        for (int s = 128; s > 0; s >>= 1) {
            if (m < s) red[m] += red[m + s];
            __syncthreads();
        }
        if (m == 0) scv[k] = red[0];
        __syncthreads();
    }
    if (m == 0) {
        float mx = fmaxf(fmaxf(scv[0], scv[1]), fmaxf(scv[2], scv[3]));
        float s = 0.0f;
        for (int k = 0; k < N_CHOICE; ++k) s += expf(scv[k] - mx);
        float ls = mx + logf(s);
        for (int k = 0; k < N_CHOICE; ++k) out[b * N_CHOICE + k] = scv[k] - ls;
    }
}

extern "C" void kernel_launch(void* const* d_in, const int* in_sizes, int n_in,
                              void* d_out, int out_size, void* d_ws, size_t ws_size,
                              hipStream_t stream) {
    const int* memory = (const int*)d_in[0];
    const int* ques = (const int*)d_in[1];
    const int* ach = (const int*)d_in[2];
    const float* A_emb = (const float*)d_in[3];
    const float* B_emb = (const float*)d_in[4];
    const float* C_emb = (const float*)d_in[5];
    const float* U = (const float*)d_in[6];
    const float* V = (const float*)d_in[7];
    const float* W = (const float*)d_in[8];
    const float* W_ih = (const float*)d_in[9];
    const float* W_hh = (const float*)d_in[10];
    const float* b_ih = (const float*)d_in[11];
    const float* b_hh = (const float*)d_in[12];
    float* out = (float*)d_out;

    /* workspace layout (floats). G0 region is reused for T/S/Opart/O after LSTM. */
    float* ws = (float*)d_ws;
    float* M_all = ws;                                    /* 3*2000*256 = 1,536,000 */
    float* G0 = M_all + 3 * N_MEM * DDIM;                 /* 3200*512   = 1,638,400 */
    float* u = G0 + (size_t)BATCH * Q_LEN * 4 * HDIM;     /* 64*256 */
    float* a = u + BATCH * EDIM;                          /* 64*4*256 */
    float* UT = a + BATCH * N_CHOICE * EDIM;              /* 256*256 */
    float* VT = UT + EDIM * DDIM;                         /* 256*256 */
    float* WhhT = VT + EDIM * DDIM;                       /* 128*512 */
    /* aliases inside the (dead after LSTM) G0 region: */
    float* T = G0;                                        /* 320*256  =    81,920 */
    float* S = T + BT * DDIM;                             /* 320*2000 =   640,000 */
    float* Opart = S + (size_t)BT * N_MEM;                /* 4*320*256 =  327,680 */
    float* O = Opart + 4 * (size_t)BT * DDIM;             /* 320*256 */

    /* 1. transposes of U, V, W_hh (hop-invariant) */
    transpose_kernel<<<dim3(8, 8), 256, 0, stream>>>(U, UT, DDIM, EDIM);
    transpose_kernel<<<dim3(8, 8), 256, 0, stream>>>(V, VT, DDIM, EDIM);
    transpose_kernel<<<dim3(4, 16), 256, 0, stream>>>(W_hh, WhhT, 4 * HDIM, HDIM);

    /* 2. memory embeddings for all hops */
    compute_M_kernel<<<dim3(N_MEM, 3), 256, 0, stream>>>(memory, A_emb, M_all);

    /* 3. LSTM input projection: G0 = B_emb[ques] @ W_ih^T + (b_ih + b_hh) */
    gemm_abT_kernel<true, true><<<dim3(50, 8), 256, 0, stream>>>(
        B_emb, W_ih, G0, BATCH * Q_LEN, 4 * HDIM, EDIM, ques, b_ih, b_hh);

    /* 4. sequential LSTM -> u = concat(h,c) */
    lstm_kernel<<<BATCH, 512, 0, stream>>>(G0, WhhT, u);

    /* 5. answer-choice embedding bags */
    answer_bag_kernel<<<dim3(N_CHOICE, BATCH), 256, 0, stream>>>(ach, C_emb, a);

    /* 6. hops */
    for (int hop = 0; hop < 3; ++hop) {
        const float* Mh = M_all + (size_t)hop * N_MEM * DDIM;
        proj_T_kernel<<<dim3(NT, BATCH), 256, 0, stream>>>(u, a, UT, VT, T);
        gemm_abT_kernel<false, false><<<dim3(5, 32), 256, 0, stream>>>(
            T, Mh, S, BT, N_MEM, DDIM, nullptr, nullptr, nullptr);
        softmax_rows_kernel<<<BT, 256, 0, stream>>>(S, N_MEM);
        gemm_ab_splitk_kernel<<<dim3(5, 4, 4), 256, 0, stream>>>(
            S, Mh, Opart, BT, DDIM, N_MEM, 512);
        reduce_update_kernel<<<BT, 256, 0, stream>>>(Opart, O, u, a);
    }

    /* 7. bilinear prediction + log_softmax */
    predict_kernel<<<BATCH, 256, 0, stream>>>(O, W, out);
}

// Round 2
// 654.455 us; speedup vs baseline: 1.2511x; 1.2511x over previous
//
#include <hip/hip_runtime.h>
#include <hip/hip_bf16.h>
#include <math.h>

#define VOCAB 50000
#define DDIM 256
#define EDIM 256
#define HDIM 128
#define N_MEM 2000
#define MEM_WORDS 50
#define BATCH 64
#define Q_LEN 50
#define N_CHOICE 4
#define CH_LEN 10
#define NT 5            /* targets per batch row: q + 4 answer choices */
#define BT (BATCH * NT) /* 320 */

__device__ __forceinline__ float sigmoidf_(float x) {
    return 1.0f / (1.0f + expf(-x));
}

/* ---------------- generic 32x32-tiled transpose: out[C][R] = in[R][C] -------- */
__global__ __launch_bounds__(256) void transpose_kernel(const float* __restrict__ in,
                                                        float* __restrict__ out,
                                                        int R, int C) {
    __shared__ float tile[32][33];
    int c0 = blockIdx.x * 32, r0 = blockIdx.y * 32;
    int tx = threadIdx.x & 31, ty = threadIdx.x >> 5; // ty: 0..7
    for (int i = ty; i < 32; i += 8) {
        int r = r0 + i, c = c0 + tx;
        tile[i][tx] = (r < R && c < C) ? in[(size_t)r * C + c] : 0.0f;
    }
    __syncthreads();
    for (int i = ty; i < 32; i += 8) {
        int r = c0 + i, c = r0 + tx; // out is [C][R]
        if (r < C && c < R) out[(size_t)r * R + c] = tile[tx][i];
    }
}

/* ---------------- M[hop][n][d] = sum_w A_emb[hop][memory[n][w]][d] ----------- */
__global__ __launch_bounds__(256) void compute_M_kernel(const int* __restrict__ memory,
                                                        const float* __restrict__ A_emb,
                                                        float* __restrict__ M_all) {
    int n = blockIdx.x, hop = blockIdx.y, d = threadIdx.x;
    __shared__ int idx[MEM_WORDS];
    if (d < MEM_WORDS) idx[d] = memory[n * MEM_WORDS + d];
    __syncthreads();
    const float* base = A_emb + (size_t)hop * VOCAB * DDIM;
    float acc = 0.0f;
#pragma unroll 5
    for (int w = 0; w < MEM_WORDS; ++w) acc += base[(size_t)idx[w] * DDIM + d];
    M_all[((size_t)hop * N_MEM + n) * DDIM + d] = acc;
}

/* ---------------- a[b][k][d] = sum_w C_emb[ach[b][k][w]][d] ------------------ */
__global__ __launch_bounds__(256) void answer_bag_kernel(const int* __restrict__ ach,
                                                         const float* __restrict__ C_emb,
                                                         float* __restrict__ a) {
    int k = blockIdx.x, b = blockIdx.y, d = threadIdx.x;
    __shared__ int idx[CH_LEN];
    if (d < CH_LEN) idx[d] = ach[(b * N_CHOICE + k) * CH_LEN + d];
    __syncthreads();
    float acc = 0.0f;
#pragma unroll
    for (int w = 0; w < CH_LEN; ++w) acc += C_emb[(size_t)idx[w] * EDIM + d];
    a[(size_t)(b * N_CHOICE + k) * EDIM + d] = acc;
}

/* ---------------- C[M][N] = A[M][K] @ B[N][K]^T (+bias), optional A-row gather */
template <bool GATHER, bool BIAS>
__global__ __launch_bounds__(256) void gemm_abT_kernel(
    const float* __restrict__ A, const float* __restrict__ B, float* __restrict__ C,
    int M, int N, int K, const int* __restrict__ gidx,
    const float* __restrict__ bias1, const float* __restrict__ bias2) {
    __shared__ float As[16][64];
    __shared__ float Bs[16][64];
    __shared__ int rows[64];
    const int tid = threadIdx.x;
    const int m0 = blockIdx.x * 64;
    const int n0 = blockIdx.y * 64;
    const int lrow = tid >> 2;       // 0..63
    const int lk = (tid & 3) << 2;   // 0,4,8,12
    const int tx = tid & 15;
    const int ty = tid >> 4;
    if (GATHER) {
        if (tid < 64) rows[tid] = gidx[m0 + tid]; // M is a multiple of 64
        __syncthreads();
    }
    float acc[4][4] = {};
    for (int k0 = 0; k0 < K; k0 += 16) {
        const float* ap = GATHER ? (A + (size_t)rows[lrow] * K)
                                 : (A + (size_t)(m0 + lrow) * K);
        float4 av = *(const float4*)(ap + k0 + lk);
        float4 bv = make_float4(0.f, 0.f, 0.f, 0.f);
        int brow = n0 + lrow;
        if (brow < N) bv = *(const float4*)(B + (size_t)brow * K + k0 + lk);
        __syncthreads();
        As[lk + 0][lrow] = av.x; As[lk + 1][lrow] = av.y;
        As[lk + 2][lrow] = av.z; As[lk + 3][lrow] = av.w;
        Bs[lk + 0][lrow] = bv.x; Bs[lk + 1][lrow] = bv.y;
        Bs[lk + 2][lrow] = bv.z; Bs[lk + 3][lrow] = bv.w;
        __syncthreads();
#pragma unroll
        for (int kk = 0; kk < 16; ++kk) {
            float4 a4 = *(const float4*)&As[kk][ty * 4];
            float4 b4 = *(const float4*)&Bs[kk][tx * 4];
            acc[0][0] += a4.x * b4.x; acc[0][1] += a4.x * b4.y; acc[0][2] += a4.x * b4.z; acc[0][3] += a4.x * b4.w;
            acc[1][0] += a4.y * b4.x; acc[1][1] += a4.y * b4.y; acc[1][2] += a4.y * b4.z; acc[1][3] += a4.y * b4.w;
            acc[2][0] += a4.z * b4.x; acc[2][1] += a4.z * b4.y; acc[2][2] += a4.z * b4.z; acc[2][3] += a4.z * b4.w;
            acc[3][0] += a4.w * b4.x; acc[3][1] += a4.w * b4.y; acc[3][2] += a4.w * b4.z; acc[3][3] += a4.w * b4.w;
        }
    }
#pragma unroll
    for (int i = 0; i < 4; ++i) {
        int m = m0 + ty * 4 + i;
#pragma unroll
        for (int j = 0; j < 4; ++j) {
            int n = n0 + tx * 4 + j;
            if (n < N) {
                float v = acc[i][j];
                if (BIAS) v += bias1[n] + bias2[n];
                C[(size_t)m * N + n] = v;
            }
        }
    }
}

/* ---------------- Cpart[z][M][N] = A[M][kchunk] @ B[kchunk][N] (split-K) ------ */
__global__ __launch_bounds__(256) void gemm_ab_splitk_kernel(
    const float* __restrict__ A, const float* __restrict__ B, float* __restrict__ Cpart,
    int M, int N, int K, int KC) {
    __shared__ float As[16][64];
    __shared__ float Bs[16][64];
    const int tid = threadIdx.x;
    const int m0 = blockIdx.x * 64;
    const int n0 = blockIdx.y * 64;
    const int kstart = blockIdx.z * KC;
    const int kend = min(K, kstart + KC); // chunk spans are multiples of 16
    const int arow = tid >> 2;
    const int alk = (tid & 3) << 2;
    const int bk = tid >> 4;         // 0..15
    const int bn = (tid & 15) << 2;  // 0..60
    const int tx = tid & 15;
    const int ty = tid >> 4;
    float acc[4][4] = {};
    for (int k0 = kstart; k0 < kend; k0 += 16) {
        float4 av = *(const float4*)(A + (size_t)(m0 + arow) * K + k0 + alk);
        float4 bv = *(const float4*)(B + (size_t)(k0 + bk) * N + n0 + bn);
        __syncthreads();
        As[alk + 0][arow] = av.x; As[alk + 1][arow] = av.y;
        As[alk + 2][arow] = av.z; As[alk + 3][arow] = av.w;
        *(float4*)&Bs[bk][bn] = bv;
        __syncthreads();
#pragma unroll
        for (int kk = 0; kk < 16; ++kk) {
            float4 a4 = *(const float4*)&As[kk][ty * 4];
            float4 b4 = *(const float4*)&Bs[kk][tx * 4];
            acc[0][0] += a4.x * b4.x; acc[0][1] += a4.x * b4.y; acc[0][2] += a4.x * b4.z; acc[0][3] += a4.x * b4.w;
            acc[1][0] += a4.y * b4.x; acc[1][1] += a4.y * b4.y; acc[1][2] += a4.y * b4.z; acc[1][3] += a4.y * b4.w;
            acc[2][0] += a4.z * b4.x; acc[2][1] += a4.z * b4.y; acc[2][2] += a4.z * b4.z; acc[2][3] += a4.z * b4.w;
            acc[3][0] += a4.w * b4.x; acc[3][1] += a4.w * b4.y; acc[3][2] += a4.w * b4.z; acc[3][3] += a4.w * b4.w;
        }
    }
    float* Cz = Cpart + (size_t)blockIdx.z * M * N;
#pragma unroll
    for (int i = 0; i < 4; ++i)
#pragma unroll
        for (int j = 0; j < 4; ++j)
            Cz[(size_t)(m0 + ty * 4 + i) * N + n0 + tx * 4 + j] = acc[i][j];
}

/* ---------------- sequential LSTM; weights cached in REGISTERS --------------- */
/* one block per batch row; thread j owns gate j and register-caches WhhT[:,j]. */
__global__ __launch_bounds__(512, 2) void lstm_kernel(const float* __restrict__ G0,
                                                      const float* __restrict__ WhhT,
                                                      float* __restrict__ u) {
    const int b = blockIdx.x;
    const int j = threadIdx.x; // 0..511 gate index
    /* register-cache column j of WhhT: 128 VGPRs, coalesced loads (consecutive
       j -> consecutive addresses). Loaded once; recurrence touches no global. */
    float w[HDIM];
#pragma unroll
    for (int h = 0; h < HDIM; ++h) w[h] = WhhT[(size_t)h * (4 * HDIM) + j];
    __shared__ float sh[HDIM];
    __shared__ float sg[4 * HDIM];
    float c = 0.0f; /* cell state lives in registers of threads j < HDIM */
    if (j < HDIM) sh[j] = 0.0f;
    __syncthreads();
    const float* g0p = G0 + (size_t)b * Q_LEN * (4 * HDIM) + j;
    for (int t = 0; t < Q_LEN; ++t) {
        /* 4 independent accumulator chains; sh read as broadcast ds_read_b128 */
        float a0 = g0p[(size_t)t * (4 * HDIM)], a1 = 0.f, a2 = 0.f, a3 = 0.f;
#pragma unroll
        for (int h = 0; h < HDIM; h += 4) {
            float4 hv = *(const float4*)&sh[h];
            a0 += w[h + 0] * hv.x;
            a1 += w[h + 1] * hv.y;
            a2 += w[h + 2] * hv.z;
            a3 += w[h + 3] * hv.w;
        }
        sg[j] = (a0 + a1) + (a2 + a3);
        __syncthreads();
        if (j < HDIM) {
            float gi = sg[j], gf = sg[HDIM + j], gg = sg[2 * HDIM + j], go = sg[3 * HDIM + j];
            c = sigmoidf_(gf) * c + sigmoidf_(gi) * tanhf(gg);
            sh[j] = sigmoidf_(go) * tanhf(c);
        }
        __syncthreads();
    }
    if (j < HDIM) {
        u[(size_t)b * EDIM + j] = sh[j];
        u[(size_t)b * EDIM + HDIM + j] = c;
    }
}

/* ---------------- T[b*5+tgt][d]: U^T proj of u (tgt 0) / V^T proj of a ------- */
__global__ __launch_bounds__(256) void proj_T_kernel(const float* __restrict__ u,
                                                     const float* __restrict__ a,
                                                     const float* __restrict__ UT,
                                                     const float* __restrict__ VT,
                                                     float* __restrict__ T) {
    const int tgt = blockIdx.x; // 0..4
    const int b = blockIdx.y;
    const int d = threadIdx.x;
    __shared__ float sx[EDIM];
    const float* src = (tgt == 0) ? (u + (size_t)b * EDIM)
                                  : (a + (size_t)(b * N_CHOICE + tgt - 1) * EDIM);
    sx[d] = src[d];
    __syncthreads();
    const float* Wt = (tgt == 0) ? UT : VT;
    float acc = 0.0f;
#pragma unroll 4
    for (int e = 0; e < EDIM; ++e) acc += Wt[(size_t)e * DDIM + d] * sx[e];
    T[(size_t)(b * NT + tgt) * DDIM + d] = acc;
}

/* ---------------- row softmax over N elements, in place ---------------------- */
__global__ __launch_bounds__(256) void softmax_rows_kernel(float* __restrict__ S, int N) {
    const int row = blockIdx.x;
    float* x = S + (size_t)row * N;
    __shared__ float red[256];
    const int tid = threadIdx.x;
    float mx = -INFINITY;
    for (int i = tid; i < N; i += 256) mx = fmaxf(mx, x[i]);
    red[tid] = mx;
    __syncthreads();
    for (int s = 128; s > 0; s >>= 1) {
        if (tid < s) red[tid] = fmaxf(red[tid], red[tid + s]);
        __syncthreads();
    }
    mx = red[0];
    __syncthreads();
    float sum = 0.0f;
    for (int i = tid; i < N; i += 256) {
        float e = expf(x[i] - mx);
        x[i] = e;
        sum += e;
    }
    red[tid] = sum;
    __syncthreads();
    for (int s = 128; s > 0; s >>= 1) {
        if (tid < s) red[tid] += red[tid + s];
        __syncthreads();
    }
    float inv = 1.0f / red[0];
    for (int i = tid; i < N; i += 256) x[i] *= inv;
}

/* ---------------- reduce split-K partials; u += o_q; a += o_a ---------------- */
__global__ __launch_bounds__(256) void reduce_update_kernel(const float* __restrict__ Opart,
                                                            float* __restrict__ O,
                                                            float* __restrict__ u,
                                                            float* __restrict__ a) {
    const int bt = blockIdx.x;
    const int d = threadIdx.x;
    const size_t idx = (size_t)bt * DDIM + d;
    const size_t stride = (size_t)BT * DDIM;
    float v = Opart[idx] + Opart[stride + idx] + Opart[2 * stride + idx] + Opart[3 * stride + idx];
    O[idx] = v;
    const int b = bt / NT, t = bt % NT;
    if (t == 0) u[(size_t)b * EDIM + d] += v;
    else a[(size_t)(b * N_CHOICE + t - 1) * EDIM + d] += v;
}

/* ---------------- pred[b][k] = o_q^T W o_a[k]; log_softmax over k ------------ */
__global__ __launch_bounds__(256) void predict_kernel(const float* __restrict__ O,
                                                      const float* __restrict__ W,
                                                      float* __restrict__ out) {
    const int b = blockIdx.x;
    const int m = threadIdx.x;
    __shared__ float soq[DDIM];
    __shared__ float red[256];
    __shared__ float scv[N_CHOICE];
    soq[m] = O[(size_t)(b * NT) * DDIM + m];
    __syncthreads();
    float wq = 0.0f;
#pragma unroll 4
    for (int d = 0; d < DDIM; ++d) wq += W[(size_t)d * DDIM + m] * soq[d];
    for (int k = 0; k < N_CHOICE; ++k) {
        red[m] = wq * O[(size_t)(b * NT + 1 + k) * DDIM + m];
        __syncthreads();
        for (int s = 128; s > 0; s >>= 1) {
            if (m < s) red[m] += red[m + s];
            __syncthreads();
        }
        if (m == 0) scv[k] = red[0];
        __syncthreads();
    }
    if (m == 0) {
        float mx = fmaxf(fmaxf(scv[0], scv[1]), fmaxf(scv[2], scv[3]));
        float s = 0.0f;
        for (int k = 0; k < N_CHOICE; ++k) s += expf(scv[k] - mx);
        float ls = mx + logf(s);
        for (int k = 0; k < N_CHOICE; ++k) out[b * N_CHOICE + k] = scv[k] - ls;
    }
}

extern "C" void kernel_launch(void* const* d_in, const int* in_sizes, int n_in,
                              void* d_out, int out_size, void* d_ws, size_t ws_size,
                              hipStream_t stream) {
    const int* memory = (const int*)d_in[0];
    const int* ques = (const int*)d_in[1];
    const int* ach = (const int*)d_in[2];
    const float* A_emb = (const float*)d_in[3];
    const float* B_emb = (const float*)d_in[4];
    const float* C_emb = (const float*)d_in[5];
    const float* U = (const float*)d_in[6];
    const float* V = (const float*)d_in[7];
    const float* W = (const float*)d_in[8];
    const float* W_ih = (const float*)d_in[9];
    const float* W_hh = (const float*)d_in[10];
    const float* b_ih = (const float*)d_in[11];
    const float* b_hh = (const float*)d_in[12];
    float* out = (float*)d_out;

    /* workspace layout (floats). G0 region is reused for T/S/Opart/O after LSTM. */
    float* ws = (float*)d_ws;
    float* M_all = ws;                                    /* 3*2000*256 = 1,536,000 */
    float* G0 = M_all + 3 * N_MEM * DDIM;                 /* 3200*512   = 1,638,400 */
    float* u = G0 + (size_t)BATCH * Q_LEN * 4 * HDIM;     /* 64*256 */
    float* a = u + BATCH * EDIM;                          /* 64*4*256 */
    float* UT = a + BATCH * N_CHOICE * EDIM;              /* 256*256 */
    float* VT = UT + EDIM * DDIM;                         /* 256*256 */
    float* WhhT = VT + EDIM * DDIM;                       /* 128*512 */
    /* aliases inside the (dead after LSTM) G0 region: */
    float* T = G0;                                        /* 320*256  =    81,920 */
    float* S = T + BT * DDIM;                             /* 320*2000 =   640,000 */
    float* Opart = S + (size_t)BT * N_MEM;                /* 4*320*256 =  327,680 */
    float* O = Opart + 4 * (size_t)BT * DDIM;             /* 320*256 */

    /* 1. transposes of U, V, W_hh (hop-invariant) */
    transpose_kernel<<<dim3(8, 8), 256, 0, stream>>>(U, UT, DDIM, EDIM);
    transpose_kernel<<<dim3(8, 8), 256, 0, stream>>>(V, VT, DDIM, EDIM);
    transpose_kernel<<<dim3(4, 16), 256, 0, stream>>>(W_hh, WhhT, 4 * HDIM, HDIM);

    /* 2. memory embeddings for all hops */
    compute_M_kernel<<<dim3(N_MEM, 3), 256, 0, stream>>>(memory, A_emb, M_all);

    /* 3. LSTM input projection: G0 = B_emb[ques] @ W_ih^T + (b_ih + b_hh) */
    gemm_abT_kernel<true, true><<<dim3(50, 8), 256, 0, stream>>>(
        B_emb, W_ih, G0, BATCH * Q_LEN, 4 * HDIM, EDIM, ques, b_ih, b_hh);

    /* 4. sequential LSTM -> u = concat(h,c) */
    lstm_kernel<<<BATCH, 512, 0, stream>>>(G0, WhhT, u);

    /* 5. answer-choice embedding bags */
    answer_bag_kernel<<<dim3(N_CHOICE, BATCH), 256, 0, stream>>>(ach, C_emb, a);

    /* 6. hops */
    for (int hop = 0; hop < 3; ++hop) {
        const float* Mh = M_all + (size_t)hop * N_MEM * DDIM;
        proj_T_kernel<<<dim3(NT, BATCH), 256, 0, stream>>>(u, a, UT, VT, T);
        gemm_abT_kernel<false, false><<<dim3(5, 32), 256, 0, stream>>>(
            T, Mh, S, BT, N_MEM, DDIM, nullptr, nullptr, nullptr);
        softmax_rows_kernel<<<BT, 256, 0, stream>>>(S, N_MEM);
        gemm_ab_splitk_kernel<<<dim3(5, 4, 4), 256, 0, stream>>>(
            S, Mh, Opart, BT, DDIM, N_MEM, 512);
        reduce_update_kernel<<<BT, 256, 0, stream>>>(Opart, O, u, a);
    }

    /* 7. bilinear prediction + log_softmax */
    predict_kernel<<<BATCH, 256, 0, stream>>>(O, W, out);
}

// Round 3
// 613.122 us; speedup vs baseline: 1.3354x; 1.0674x over previous
//
#include <hip/hip_runtime.h>
#include <hip/hip_bf16.h>
#include <math.h>

#define VOCAB 50000
#define DDIM 256
#define EDIM 256
#define HDIM 128
#define N_MEM 2000
#define MEM_WORDS 50
#define BATCH 64
#define Q_LEN 50
#define N_CHOICE 4
#define CH_LEN 10
#define NT 5            /* targets per batch row: q + 4 answer choices */
#define BT (BATCH * NT) /* 320 */
#define OZ 10           /* split-K factor for O-GEMM */
#define OKC 208         /* K-chunk (multiple of 16; 9*208 + 128 = 2000) */

__device__ __forceinline__ float sigmoidf_(float x) {
    return 1.0f / (1.0f + expf(-x));
}

/* ---------------- generic 32x32-tiled transpose: out[C][R] = in[R][C] -------- */
__global__ __launch_bounds__(256) void transpose_kernel(const float* __restrict__ in,
                                                        float* __restrict__ out,
                                                        int R, int C) {
    __shared__ float tile[32][33];
    int c0 = blockIdx.x * 32, r0 = blockIdx.y * 32;
    int tx = threadIdx.x & 31, ty = threadIdx.x >> 5; // ty: 0..7
    for (int i = ty; i < 32; i += 8) {
        int r = r0 + i, c = c0 + tx;
        tile[i][tx] = (r < R && c < C) ? in[(size_t)r * C + c] : 0.0f;
    }
    __syncthreads();
    for (int i = ty; i < 32; i += 8) {
        int r = c0 + i, c = r0 + tx; // out is [C][R]
        if (r < C && c < R) out[(size_t)r * R + c] = tile[tx][i];
    }
}

/* ------- M[hop][n][d] = sum_w A_emb[hop][memory[n][w]][d]; float4 lanes ------ */
/* block: 256 threads = 4 memory slots x 64 lanes (lane covers 4 d's). */
__global__ __launch_bounds__(256) void compute_M_kernel(const int* __restrict__ memory,
                                                        const float* __restrict__ A_emb,
                                                        float* __restrict__ M_all) {
    const int hop = blockIdx.y;
    const int tid = threadIdx.x;
    const int slot = tid >> 6;        // 0..3
    const int lane = tid & 63;        // 0..63
    const int n = blockIdx.x * 4 + slot;
    __shared__ int sidx[4 * MEM_WORDS];
    if (tid < 4 * MEM_WORDS) sidx[tid] = memory[blockIdx.x * 4 * MEM_WORDS + tid];
    __syncthreads();
    const float* base = A_emb + (size_t)hop * VOCAB * DDIM + (lane << 2);
    float4 acc = make_float4(0.f, 0.f, 0.f, 0.f);
#pragma unroll 10
    for (int w = 0; w < MEM_WORDS; ++w) {
        float4 v = *(const float4*)(base + (size_t)sidx[slot * MEM_WORDS + w] * DDIM);
        acc.x += v.x; acc.y += v.y; acc.z += v.z; acc.w += v.w;
    }
    *(float4*)&M_all[((size_t)hop * N_MEM + n) * DDIM + (lane << 2)] = acc;
}

/* ---------------- a[b][k][d] = sum_w C_emb[ach[b][k][w]][d] ------------------ */
__global__ __launch_bounds__(256) void answer_bag_kernel(const int* __restrict__ ach,
                                                         const float* __restrict__ C_emb,
                                                         float* __restrict__ a) {
    int k = blockIdx.x, b = blockIdx.y, d = threadIdx.x;
    __shared__ int idx[CH_LEN];
    if (d < CH_LEN) idx[d] = ach[(b * N_CHOICE + k) * CH_LEN + d];
    __syncthreads();
    float acc = 0.0f;
#pragma unroll
    for (int w = 0; w < CH_LEN; ++w) acc += C_emb[(size_t)idx[w] * EDIM + d];
    a[(size_t)(b * N_CHOICE + k) * EDIM + d] = acc;
}

/* ------- C[M][N] = A[M][K] @ B[N][K]^T (+bias), optional A-row gather -------- */
/* 32x64 tile, 128 threads (2 waves), 4x4 micro-tile. Padded LDS (no 4-way    */
/* conflicts, 16B-aligned rows for b128 reads).                                */
template <bool GATHER, bool BIAS>
__global__ __launch_bounds__(128) void gemm32_abT_kernel(
    const float* __restrict__ A, const float* __restrict__ B, float* __restrict__ C,
    int M, int N, int K, const int* __restrict__ gidx,
    const float* __restrict__ bias1, const float* __restrict__ bias2) {
    __shared__ float As[16][36];   // k-major, padded (36*4=144B rows, 16B aligned)
    __shared__ float Bs[16][68];   // k-major, padded (68*4=272B rows, 16B aligned)
    __shared__ int rows[32];
    const int tid = threadIdx.x;
    const int m0 = blockIdx.x * 32;
    const int n0 = blockIdx.y * 64;
    const int arow = tid >> 2;        // 0..31
    const int ak4 = (tid & 3) << 2;   // 0,4,8,12
    const int tx = tid & 15;          // B col group
    const int ty = tid >> 4;          // A row group 0..7
    if (GATHER) {
        if (tid < 32) rows[tid] = gidx[m0 + tid]; // M is a multiple of 32
        __syncthreads();
    }
    float acc[4][4] = {};
    for (int k0 = 0; k0 < K; k0 += 16) {
        const float* ap = GATHER ? (A + (size_t)rows[arow] * K)
                                 : (A + (size_t)(m0 + arow) * K);
        float4 av = *(const float4*)(ap + k0 + ak4);
        float4 bv0 = make_float4(0.f, 0.f, 0.f, 0.f);
        float4 bv1 = make_float4(0.f, 0.f, 0.f, 0.f);
        int br0 = n0 + arow, br1 = n0 + 32 + arow;
        if (br0 < N) bv0 = *(const float4*)(B + (size_t)br0 * K + k0 + ak4);
        if (br1 < N) bv1 = *(const float4*)(B + (size_t)br1 * K + k0 + ak4);
        __syncthreads();
        As[ak4 + 0][arow] = av.x; As[ak4 + 1][arow] = av.y;
        As[ak4 + 2][arow] = av.z; As[ak4 + 3][arow] = av.w;
        Bs[ak4 + 0][arow] = bv0.x; Bs[ak4 + 1][arow] = bv0.y;
        Bs[ak4 + 2][arow] = bv0.z; Bs[ak4 + 3][arow] = bv0.w;
        Bs[ak4 + 0][32 + arow] = bv1.x; Bs[ak4 + 1][32 + arow] = bv1.y;
        Bs[ak4 + 2][32 + arow] = bv1.z; Bs[ak4 + 3][32 + arow] = bv1.w;
        __syncthreads();
#pragma unroll
        for (int kk = 0; kk < 16; ++kk) {
            float4 a4 = *(const float4*)&As[kk][ty * 4];
            float4 b4 = *(const float4*)&Bs[kk][tx * 4];
            acc[0][0] += a4.x * b4.x; acc[0][1] += a4.x * b4.y; acc[0][2] += a4.x * b4.z; acc[0][3] += a4.x * b4.w;
            acc[1][0] += a4.y * b4.x; acc[1][1] += a4.y * b4.y; acc[1][2] += a4.y * b4.z; acc[1][3] += a4.y * b4.w;
            acc[2][0] += a4.z * b4.x; acc[2][1] += a4.z * b4.y; acc[2][2] += a4.z * b4.z; acc[2][3] += a4.z * b4.w;
            acc[3][0] += a4.w * b4.x; acc[3][1] += a4.w * b4.y; acc[3][2] += a4.w * b4.z; acc[3][3] += a4.w * b4.w;
        }
    }
#pragma unroll
    for (int i = 0; i < 4; ++i) {
        int m = m0 + ty * 4 + i;
#pragma unroll
        for (int j = 0; j < 4; ++j) {
            int n = n0 + tx * 4 + j;
            if (n < N) {
                float v = acc[i][j];
                if (BIAS) v += bias1[n] + bias2[n];
                C[(size_t)m * N + n] = v;
            }
        }
    }
}

/* ------- Cpart[z][M][N] = A[M][kchunk] @ B[kchunk][N] (split-K, 32x64) ------- */
__global__ __launch_bounds__(128) void gemm32_ab_splitk_kernel(
    const float* __restrict__ A, const float* __restrict__ B, float* __restrict__ Cpart,
    int M, int N, int K, int KC) {
    __shared__ float As[16][36];
    __shared__ float Bs[16][68];
    const int tid = threadIdx.x;
    const int m0 = blockIdx.x * 32;
    const int n0 = blockIdx.y * 64;
    const int kstart = blockIdx.z * KC;
    const int kend = min(K, kstart + KC); // chunk spans are multiples of 16
    const int arow = tid >> 2;        // 0..31
    const int ak4 = (tid & 3) << 2;   // 0,4,8,12
    const int bk = tid >> 4;          // 0..7
    const int bn = (tid & 15) << 2;   // 0..60
    const int tx = tid & 15;
    const int ty = tid >> 4;
    float acc[4][4] = {};
    for (int k0 = kstart; k0 < kend; k0 += 16) {
        float4 av = *(const float4*)(A + (size_t)(m0 + arow) * K + k0 + ak4);
        float4 bv0 = *(const float4*)(B + (size_t)(k0 + bk) * N + n0 + bn);
        float4 bv1 = *(const float4*)(B + (size_t)(k0 + bk + 8) * N + n0 + bn);
        __syncthreads();
        As[ak4 + 0][arow] = av.x; As[ak4 + 1][arow] = av.y;
        As[ak4 + 2][arow] = av.z; As[ak4 + 3][arow] = av.w;
        *(float4*)&Bs[bk][bn] = bv0;
        *(float4*)&Bs[bk + 8][bn] = bv1;
        __syncthreads();
#pragma unroll
        for (int kk = 0; kk < 16; ++kk) {
            float4 a4 = *(const float4*)&As[kk][ty * 4];
            float4 b4 = *(const float4*)&Bs[kk][tx * 4];
            acc[0][0] += a4.x * b4.x; acc[0][1] += a4.x * b4.y; acc[0][2] += a4.x * b4.z; acc[0][3] += a4.x * b4.w;
            acc[1][0] += a4.y * b4.x; acc[1][1] += a4.y * b4.y; acc[1][2] += a4.y * b4.z; acc[1][3] += a4.y * b4.w;
            acc[2][0] += a4.z * b4.x; acc[2][1] += a4.z * b4.y; acc[2][2] += a4.z * b4.z; acc[2][3] += a4.z * b4.w;
            acc[3][0] += a4.w * b4.x; acc[3][1] += a4.w * b4.y; acc[3][2] += a4.w * b4.z; acc[3][3] += a4.w * b4.w;
        }
    }
    float* Cz = Cpart + (size_t)blockIdx.z * M * N;
#pragma unroll
    for (int i = 0; i < 4; ++i)
#pragma unroll
        for (int j = 0; j < 4; ++j)
            Cz[(size_t)(m0 + ty * 4 + i) * N + n0 + tx * 4 + j] = acc[i][j];
}

/* ---------------- sequential LSTM; weights cached in REGISTERS --------------- */
__global__ __launch_bounds__(512, 2) void lstm_kernel(const float* __restrict__ G0,
                                                      const float* __restrict__ WhhT,
                                                      float* __restrict__ u) {
    const int b = blockIdx.x;
    const int j = threadIdx.x; // 0..511 gate index
    float w[HDIM];
#pragma unroll
    for (int h = 0; h < HDIM; ++h) w[h] = WhhT[(size_t)h * (4 * HDIM) + j];
    __shared__ float sh[HDIM];
    __shared__ float sg[4 * HDIM];
    float c = 0.0f;
    if (j < HDIM) sh[j] = 0.0f;
    __syncthreads();
    const float* g0p = G0 + (size_t)b * Q_LEN * (4 * HDIM) + j;
    for (int t = 0; t < Q_LEN; ++t) {
        float a0 = g0p[(size_t)t * (4 * HDIM)], a1 = 0.f, a2 = 0.f, a3 = 0.f;
#pragma unroll
        for (int h = 0; h < HDIM; h += 4) {
            float4 hv = *(const float4*)&sh[h];
            a0 += w[h + 0] * hv.x;
            a1 += w[h + 1] * hv.y;
            a2 += w[h + 2] * hv.z;
            a3 += w[h + 3] * hv.w;
        }
        sg[j] = (a0 + a1) + (a2 + a3);
        __syncthreads();
        if (j < HDIM) {
            float gi = sg[j], gf = sg[HDIM + j], gg = sg[2 * HDIM + j], go = sg[3 * HDIM + j];
            c = sigmoidf_(gf) * c + sigmoidf_(gi) * tanhf(gg);
            sh[j] = sigmoidf_(go) * tanhf(c);
        }
        __syncthreads();
    }
    if (j < HDIM) {
        u[(size_t)b * EDIM + j] = sh[j];
        u[(size_t)b * EDIM + HDIM + j] = c;
    }
}

/* ---------------- T[b*5+tgt][d]: U^T proj of u (tgt 0) / V^T proj of a ------- */
__global__ __launch_bounds__(256) void proj_T_kernel(const float* __restrict__ u,
                                                     const float* __restrict__ a,
                                                     const float* __restrict__ UT,
                                                     const float* __restrict__ VT,
                                                     float* __restrict__ T) {
    const int tgt = blockIdx.x; // 0..4
    const int b = blockIdx.y;
    const int d = threadIdx.x;
    __shared__ float sx[EDIM];
    const float* src = (tgt == 0) ? (u + (size_t)b * EDIM)
                                  : (a + (size_t)(b * N_CHOICE + tgt - 1) * EDIM);
    sx[d] = src[d];
    __syncthreads();
    const float* Wt = (tgt == 0) ? UT : VT;
    float acc = 0.0f;
#pragma unroll 4
    for (int e = 0; e < EDIM; ++e) acc += Wt[(size_t)e * DDIM + d] * sx[e];
    T[(size_t)(b * NT + tgt) * DDIM + d] = acc;
}

/* ---- row softmax numerator: x = exp(x - max); sums[row] = sum (no scale) ---- */
__global__ __launch_bounds__(256) void softmax_rows_kernel(float* __restrict__ S,
                                                           float* __restrict__ sums, int N) {
    const int row = blockIdx.x;
    float* x = S + (size_t)row * N;
    __shared__ float red[256];
    const int tid = threadIdx.x;
    float mx = -INFINITY;
    for (int i = tid; i < N; i += 256) mx = fmaxf(mx, x[i]);
    red[tid] = mx;
    __syncthreads();
    for (int s = 128; s > 0; s >>= 1) {
        if (tid < s) red[tid] = fmaxf(red[tid], red[tid + s]);
        __syncthreads();
    }
    mx = red[0];
    __syncthreads();
    float sum = 0.0f;
    for (int i = tid; i < N; i += 256) {
        float e = expf(x[i] - mx);
        x[i] = e;
        sum += e;
    }
    red[tid] = sum;
    __syncthreads();
    for (int s = 128; s > 0; s >>= 1) {
        if (tid < s) red[tid] += red[tid + s];
        __syncthreads();
    }
    if (tid == 0) sums[row] = red[0];
}

/* ------- reduce split-K partials; normalize by softmax sum; u+=, a+= --------- */
__global__ __launch_bounds__(256) void reduce_update_kernel(const float* __restrict__ Opart,
                                                            const float* __restrict__ sums,
                                                            float* __restrict__ O,
                                                            float* __restrict__ u,
                                                            float* __restrict__ a) {
    const int bt = blockIdx.x;
    const int d = threadIdx.x;
    const size_t idx = (size_t)bt * DDIM + d;
    const size_t stride = (size_t)BT * DDIM;
    float v = 0.0f;
#pragma unroll
    for (int z = 0; z < OZ; ++z) v += Opart[z * stride + idx];
    v /= sums[bt];
    O[idx] = v;
    const int b = bt / NT, t = bt % NT;
    if (t == 0) u[(size_t)b * EDIM + d] += v;
    else a[(size_t)(b * N_CHOICE + t - 1) * EDIM + d] += v;
}

/* ---------------- pred[b][k] = o_q^T W o_a[k]; log_softmax over k ------------ */
__global__ __launch_bounds__(256) void predict_kernel(const float* __restrict__ O,
                                                      const float* __restrict__ W,
                                                      float* __restrict__ out) {
    const int b = blockIdx.x;
    const int m = threadIdx.x;
    __shared__ float soq[DDIM];
    __shared__ float red[256];
    __shared__ float scv[N_CHOICE];
    soq[m] = O[(size_t)(b * NT) * DDIM + m];
    __syncthreads();
    float wq = 0.0f;
#pragma unroll 4
    for (int d = 0; d < DDIM; ++d) wq += W[(size_t)d * DDIM + m] * soq[d];
    for (int k = 0; k < N_CHOICE; ++k) {
        red[m] = wq * O[(size_t)(b * NT + 1 + k) * DDIM + m];
        __syncthreads();
        for (int s = 128; s > 0; s >>= 1) {
            if (m < s) red[m] += red[m + s];
            __syncthreads();
        }
        if (m == 0) scv[k] = red[0];
        __syncthreads();
    }
    if (m == 0) {
        float mx = fmaxf(fmaxf(scv[0], scv[1]), fmaxf(scv[2], scv[3]));
        float s = 0.0f;
        for (int k = 0; k < N_CHOICE; ++k) s += expf(scv[k] - mx);
        float ls = mx + logf(s);
        for (int k = 0; k < N_CHOICE; ++k) out[b * N_CHOICE + k] = scv[k] - ls;
    }
}

extern "C" void kernel_launch(void* const* d_in, const int* in_sizes, int n_in,
                              void* d_out, int out_size, void* d_ws, size_t ws_size,
                              hipStream_t stream) {
    const int* memory = (const int*)d_in[0];
    const int* ques = (const int*)d_in[1];
    const int* ach = (const int*)d_in[2];
    const float* A_emb = (const float*)d_in[3];
    const float* B_emb = (const float*)d_in[4];
    const float* C_emb = (const float*)d_in[5];
    const float* U = (const float*)d_in[6];
    const float* V = (const float*)d_in[7];
    const float* W = (const float*)d_in[8];
    const float* W_ih = (const float*)d_in[9];
    const float* W_hh = (const float*)d_in[10];
    const float* b_ih = (const float*)d_in[11];
    const float* b_hh = (const float*)d_in[12];
    float* out = (float*)d_out;

    /* workspace layout (floats). G0 region is reused for T/S/sums/Opart/O later */
    float* ws = (float*)d_ws;
    float* M_all = ws;                                    /* 3*2000*256 = 1,536,000 */
    float* G0 = M_all + 3 * N_MEM * DDIM;                 /* 3200*512   = 1,638,400 */
    float* u = G0 + (size_t)BATCH * Q_LEN * 4 * HDIM;     /* 64*256 */
    float* a = u + BATCH * EDIM;                          /* 64*4*256 */
    float* UT = a + BATCH * N_CHOICE * EDIM;              /* 256*256 */
    float* VT = UT + EDIM * DDIM;                         /* 256*256 */
    float* WhhT = VT + EDIM * DDIM;                       /* 128*512 */
    /* aliases inside the (dead after LSTM) G0 region: */
    float* T = G0;                                        /* 320*256   =    81,920 */
    float* S = T + BT * DDIM;                             /* 320*2000  =   640,000 */
    float* sums = S + (size_t)BT * N_MEM;                 /* 320 */
    float* Opart = sums + BT;                             /* 10*320*256 =  819,200 */
    float* O = Opart + (size_t)OZ * BT * DDIM;            /* 320*256 */

    /* 1. transposes of U, V, W_hh (hop-invariant) */
    transpose_kernel<<<dim3(8, 8), 256, 0, stream>>>(U, UT, DDIM, EDIM);
    transpose_kernel<<<dim3(8, 8), 256, 0, stream>>>(V, VT, DDIM, EDIM);
    transpose_kernel<<<dim3(4, 16), 256, 0, stream>>>(W_hh, WhhT, 4 * HDIM, HDIM);

    /* 2. memory embeddings for all hops (float4 lanes, 4 slots/block) */
    compute_M_kernel<<<dim3(N_MEM / 4, 3), 256, 0, stream>>>(memory, A_emb, M_all);

    /* 3. LSTM input projection: G0 = B_emb[ques] @ W_ih^T + (b_ih + b_hh) */
    gemm32_abT_kernel<true, true><<<dim3(100, 8), 128, 0, stream>>>(
        B_emb, W_ih, G0, BATCH * Q_LEN, 4 * HDIM, EDIM, ques, b_ih, b_hh);

    /* 4. sequential LSTM -> u = concat(h,c) */
    lstm_kernel<<<BATCH, 512, 0, stream>>>(G0, WhhT, u);

    /* 5. answer-choice embedding bags */
    answer_bag_kernel<<<dim3(N_CHOICE, BATCH), 256, 0, stream>>>(ach, C_emb, a);

    /* 6. hops */
    for (int hop = 0; hop < 3; ++hop) {
        const float* Mh = M_all + (size_t)hop * N_MEM * DDIM;
        proj_T_kernel<<<dim3(NT, BATCH), 256, 0, stream>>>(u, a, UT, VT, T);
        gemm32_abT_kernel<false, false><<<dim3(10, 32), 128, 0, stream>>>(
            T, Mh, S, BT, N_MEM, DDIM, nullptr, nullptr, nullptr);
        softmax_rows_kernel<<<BT, 256, 0, stream>>>(S, sums, N_MEM);
        gemm32_ab_splitk_kernel<<<dim3(10, 4, OZ), 128, 0, stream>>>(
            S, Mh, Opart, BT, DDIM, N_MEM, OKC);
        reduce_update_kernel<<<BT, 256, 0, stream>>>(Opart, sums, O, u, a);
    }

    /* 7. bilinear prediction + log_softmax */
    predict_kernel<<<BATCH, 256, 0, stream>>>(O, W, out);
}